// Round 5
// baseline (465.224 us; speedup 1.0000x reference)
//
#include <hip/hip_runtime.h>
#include <hip/hip_bf16.h>

#define NN 4096
#define IN_F 256
#define OUT_F 128
#define ALPHA 0.2f

typedef __bf16 bf16x8 __attribute__((ext_vector_type(8)));
typedef float f32x4 __attribute__((ext_vector_type(4)));
typedef float f32x16 __attribute__((ext_vector_type(16)));

__device__ __forceinline__ float bf2f(unsigned short u) {
  return __uint_as_float(((unsigned int)u) << 16);
}
__device__ __forceinline__ unsigned short f2bf(float f) {
  union { float f; unsigned int u; } x; x.f = f;
  unsigned int r = x.u + 0x7FFF + ((x.u >> 16) & 1);
  return (unsigned short)(r >> 16);
}
// 8 bits -> 8 bf16 values in {0.0, 1.0}
__device__ __forceinline__ bf16x8 bits2bf8(unsigned int b) {
  union { unsigned int u[4]; bf16x8 v; } o;
  #pragma unroll
  for (int e = 0; e < 4; ++e) {
    unsigned int lo = (b >> (2 * e)) & 1u;
    unsigned int hi = (b >> (2 * e + 1)) & 1u;
    o.u[e] = lo * 0x3F80u + hi * 0x3F800000u;
  }
  return o.v;
}

// ---- converts ----
__global__ __launch_bounds__(256) void k_cvt_h(const float* __restrict__ h,
                                               unsigned short* __restrict__ hb) {
  int idx = (blockIdx.x * 256 + threadIdx.x) * 8;
  float4 v0 = *(const float4*)(h + idx);
  float4 v1 = *(const float4*)(h + idx + 4);
  union { unsigned short u[8]; uint4 q; } o;
  o.u[0] = f2bf(v0.x); o.u[1] = f2bf(v0.y); o.u[2] = f2bf(v0.z); o.u[3] = f2bf(v0.w);
  o.u[4] = f2bf(v1.x); o.u[5] = f2bf(v1.y); o.u[6] = f2bf(v1.z); o.u[7] = f2bf(v1.w);
  *(uint4*)(hb + idx) = o.q;
}

__global__ __launch_bounds__(256) void k_cvt_w(const float* __restrict__ W,
                                               unsigned short* __restrict__ Wtb) {
  const int i = blockIdx.y;
  const int k0 = blockIdx.x * 32;
  const int t = threadIdx.x;
  __shared__ float tile[32][129];
  #pragma unroll
  for (int j = 0; j < 16; ++j) {
    int idx = t + j * 256;
    int r = idx >> 7, c = idx & 127;
    tile[r][c] = W[(size_t)(i * IN_F + k0 + r) * OUT_F + c];
  }
  __syncthreads();
  const int c = t >> 1, half = t & 1;
  unsigned short* dst = Wtb + ((size_t)i * OUT_F + c) * IN_F + k0 + half * 16;
  #pragma unroll
  for (int g = 0; g < 4; ++g) {
    ushort4 v;
    v.x = f2bf(tile[half * 16 + g * 4 + 0][c]);
    v.y = f2bf(tile[half * 16 + g * 4 + 1][c]);
    v.z = f2bf(tile[half * 16 + g * 4 + 2][c]);
    v.w = f2bf(tile[half * 16 + g * 4 + 3][c]);
    *(ushort4*)(dst + g * 4) = v;
  }
}

__global__ __launch_bounds__(256) void k_zero(float* __restrict__ p) {
  int idx = blockIdx.x * 256 + threadIdx.x;
  f32x4 z = {0.f, 0.f, 0.f, 0.f};
  *(f32x4*)(p + (size_t)idx * 4) = z;
}

// ---- K1: Whnewf[i] = h @ W_i (MFMA) + Wh1/Wh2 vectors ----
__global__ __launch_bounds__(256) void k_front(const unsigned short* __restrict__ hb,
                                               const unsigned short* __restrict__ Wtb,
                                               const float* __restrict__ a,
                                               float* __restrict__ Whnewf,
                                               float* __restrict__ Wh1,
                                               float* __restrict__ Wh2) {
  const int i = blockIdx.y;
  const int r0 = blockIdx.x * 32;
  const int t = threadIdx.x;
  const int lane = t & 63, wid = t >> 6;
  const int m = wid & 1, nh = wid >> 1, nbase = nh * 64;
  const int ln = lane & 15, lk = lane >> 4;

  __shared__ float a1s[128], a2s[128];
  __shared__ float red1[2][32], red2[2][32];

  if (t < 128) {
    a1s[t] = a[(size_t)2 * i * OUT_F + t];
    a2s[t] = a[(size_t)(2 * i + 1) * OUT_F + t];
  }
  __syncthreads();

  const unsigned short* ap = hb + (size_t)(r0 + m * 16 + ln) * IN_F + lk * 8;
  const unsigned short* bp = Wtb + ((size_t)i * OUT_F + nbase + ln) * IN_F + lk * 8;

  f32x4 z4 = {0.f, 0.f, 0.f, 0.f};
  f32x4 acc[4] = {z4, z4, z4, z4};
  #pragma unroll
  for (int ks = 0; ks < 8; ++ks) {
    bf16x8 av = *(const bf16x8*)(ap + ks * 32);
    acc[0] = __builtin_amdgcn_mfma_f32_16x16x32_bf16(av, *(const bf16x8*)(bp + 0 * 16 * IN_F + ks * 32), acc[0], 0, 0, 0);
    acc[1] = __builtin_amdgcn_mfma_f32_16x16x32_bf16(av, *(const bf16x8*)(bp + 1 * 16 * IN_F + ks * 32), acc[1], 0, 0, 0);
    acc[2] = __builtin_amdgcn_mfma_f32_16x16x32_bf16(av, *(const bf16x8*)(bp + 2 * 16 * IN_F + ks * 32), acc[2], 0, 0, 0);
    acc[3] = __builtin_amdgcn_mfma_f32_16x16x32_bf16(av, *(const bf16x8*)(bp + 3 * 16 * IN_F + ks * 32), acc[3], 0, 0, 0);
  }

  float d1[4] = {0.f, 0.f, 0.f, 0.f}, d2[4] = {0.f, 0.f, 0.f, 0.f};
  #pragma unroll
  for (int f = 0; f < 4; ++f) {
    const int col = nbase + f * 16 + ln;
    const float va1 = a1s[col], va2 = a2s[col];
    #pragma unroll
    for (int q = 0; q < 4; ++q) {
      const int row = m * 16 + lk * 4 + q;
      const float v = acc[f][q];
      Whnewf[((size_t)i * NN + r0 + row) * OUT_F + col] = v;
      d1[q] += v * va1;
      d2[q] += v * va2;
    }
  }
  #pragma unroll
  for (int msk = 1; msk < 16; msk <<= 1) {
    #pragma unroll
    for (int q = 0; q < 4; ++q) {
      d1[q] += __shfl_xor(d1[q], msk, 64);
      d2[q] += __shfl_xor(d2[q], msk, 64);
    }
  }
  if (ln == 0) {
    #pragma unroll
    for (int q = 0; q < 4; ++q) {
      red1[nh][m * 16 + lk * 4 + q] = d1[q];
      red2[nh][m * 16 + lk * 4 + q] = d2[q];
    }
  }
  __syncthreads();
  if (t < 32) {
    Wh1[(size_t)i * NN + r0 + t] = red1[0][t] + red1[1][t];
    Wh2[(size_t)i * NN + r0 + t] = red2[0][t] + red2[1][t];
  }
}

// ---- gmax2[i] = max_c Wh2[i][c] ----
__global__ __launch_bounds__(256) void k_gmax(const float* __restrict__ Wh2,
                                              float* __restrict__ gmax2) {
  const int i = blockIdx.x;
  const int t = threadIdx.x;
  __shared__ float red[4];
  float m = -3.0e38f;
  #pragma unroll
  for (int j = 0; j < 16; ++j) m = fmaxf(m, Wh2[(size_t)i * NN + t + j * 256]);
  #pragma unroll
  for (int o = 32; o > 0; o >>= 1) m = fmaxf(m, __shfl_down(m, o, 64));
  if ((t & 63) == 0) red[t >> 6] = m;
  __syncthreads();
  if (t == 0) gmax2[i] = fmaxf(fmaxf(red[0], red[1]), fmaxf(red[2], red[3]));
}

// ---- ew2pb[i][c] = bf16(e^{w2c}), ew2mb = bf16(e^{alpha w2c}) ----
__global__ __launch_bounds__(256) void k_ew2(const float* __restrict__ Wh2,
                                             unsigned short* __restrict__ ew2pb,
                                             unsigned short* __restrict__ ew2mb) {
  int id = blockIdx.x * 256 + threadIdx.x;
  float w2 = Wh2[id];
  ew2pb[id] = f2bf(__expf(w2));
  ew2mb[id] = f2bf(__expf(ALPHA * w2));
}

// ---- Vkm[i][s][n][c] = bf16( float(ew2b[s][c]) * Whnewf[i][c][n] ) ----
__global__ __launch_bounds__(256) void k_scale(const float* __restrict__ Whnewf,
                                               const unsigned short* __restrict__ ew2pb,
                                               const unsigned short* __restrict__ ew2mb,
                                               unsigned short* __restrict__ Vkm) {
  const int i = blockIdx.y;
  const int k0 = blockIdx.x * 32;
  const int t = threadIdx.x;
  __shared__ float tile[32][129];
  __shared__ float ewsp[32], ewsm[32];
  if (t < 32) {
    ewsp[t] = bf2f(ew2pb[(size_t)i * NN + k0 + t]);
    ewsm[t] = bf2f(ew2mb[(size_t)i * NN + k0 + t]);
  }
  #pragma unroll
  for (int j = 0; j < 16; ++j) {
    int idx = t + j * 256;
    int r = idx >> 7, c = idx & 127;
    tile[r][c] = Whnewf[((size_t)i * NN + k0 + r) * OUT_F + c];
  }
  __syncthreads();
  const int n = t >> 1, half = t & 1;
  unsigned short* dstP = Vkm + ((size_t)(i * 2 + 0) * OUT_F + n) * NN + k0 + half * 16;
  unsigned short* dstM = Vkm + ((size_t)(i * 2 + 1) * OUT_F + n) * NN + k0 + half * 16;
  #pragma unroll
  for (int g = 0; g < 4; ++g) {
    ushort4 vp, vm;
    float x0 = tile[half * 16 + g * 4 + 0][n];
    float x1 = tile[half * 16 + g * 4 + 1][n];
    float x2 = tile[half * 16 + g * 4 + 2][n];
    float x3 = tile[half * 16 + g * 4 + 3][n];
    vp.x = f2bf(ewsp[half * 16 + g * 4 + 0] * x0);
    vp.y = f2bf(ewsp[half * 16 + g * 4 + 1] * x1);
    vp.z = f2bf(ewsp[half * 16 + g * 4 + 2] * x2);
    vp.w = f2bf(ewsp[half * 16 + g * 4 + 3] * x3);
    vm.x = f2bf(ewsm[half * 16 + g * 4 + 0] * x0);
    vm.y = f2bf(ewsm[half * 16 + g * 4 + 1] * x1);
    vm.z = f2bf(ewsm[half * 16 + g * 4 + 2] * x2);
    vm.w = f2bf(ewsm[half * 16 + g * 4 + 3] * x3);
    *(ushort4*)(dstP + g * 4) = vp;
    *(ushort4*)(dstM + g * 4) = vm;
  }
}

// ---- PASS 1: stream mask once -> bit matrices + row sums S+/S-. grid (512,3). ----
__global__ __launch_bounds__(256) void k_bits(const int* __restrict__ mask,
                                              const float* __restrict__ Wh1,
                                              const float* __restrict__ Wh2,
                                              const unsigned short* __restrict__ ew2pb,
                                              const unsigned short* __restrict__ ew2mb,
                                              unsigned int* __restrict__ Bits,
                                              float* __restrict__ Sp,
                                              float* __restrict__ Sm) {
  const int i = blockIdx.y;
  const int r0 = blockIdx.x * 8;
  const int t = threadIdx.x;
  const int lane = t & 63, wid = t >> 6;
  __shared__ float partP[8][4], partM[8][4];
  float w2v[16], ep[16], em[16];
  #pragma unroll
  for (int j = 0; j < 16; ++j) {
    int c = t * 16 + j;
    w2v[j] = Wh2[(size_t)i * NN + c];
    ep[j] = bf2f(ew2pb[(size_t)i * NN + c]);
    em[j] = bf2f(ew2mb[(size_t)i * NN + c]);
  }
  const int* mbase = mask + ((size_t)i * NN + r0) * NN + t * 16;
  int mA[16], mB[16];
  auto LD = [&](int rr, int* mv) {
    #pragma unroll
    for (int jj = 0; jj < 4; ++jj) {
      int4 v = *(const int4*)(mbase + (size_t)rr * NN + jj * 4);
      mv[jj * 4 + 0] = v.x; mv[jj * 4 + 1] = v.y;
      mv[jj * 4 + 2] = v.z; mv[jj * 4 + 3] = v.w;
    }
  };
  auto PR = [&](int rr, const int* mv) {
    const int r = r0 + rr;
    const float nw1 = -Wh1[(size_t)i * NN + r];
    unsigned int bp = 0, bm = 0;
    float sp = 0.f, sm = 0.f;
    #pragma unroll
    for (int j = 0; j < 16; ++j) {
      bool mm = mv[j] > 0;
      bool cc = w2v[j] > nw1;
      if (mm && cc)  { bp |= 1u << j; sp += ep[j]; }
      if (mm && !cc) { bm |= 1u << j; sm += em[j]; }
    }
    Bits[((size_t)i * NN + r) * 256 + t] = bp | (bm << 16);
    #pragma unroll
    for (int o = 1; o < 64; o <<= 1) {
      sp += __shfl_xor(sp, o, 64);
      sm += __shfl_xor(sm, o, 64);
    }
    if (lane == 0) { partP[rr][wid] = sp; partM[rr][wid] = sm; }
  };
  LD(0, mA);
  #pragma unroll
  for (int rp = 0; rp < 4; ++rp) {
    LD(2 * rp + 1, mB);
    PR(2 * rp, mA);
    if (rp < 3) LD(2 * rp + 2, mA);
    PR(2 * rp + 1, mB);
  }
  __syncthreads();
  if (t < 8) {
    Sp[(size_t)i * NN + r0 + t] = partP[t][0] + partP[t][1] + partP[t][2] + partP[t][3];
    Sm[(size_t)i * NN + r0 + t] = partM[t][0] + partM[t][1] + partM[t][2] + partM[t][3];
  }
}

// ---- PASS 2: U += f+ * (P+ @ V+) + f- * (P- @ V-) via 32x32x16 MFMA.
// grid (64, 3, 4): 64 rows x 1024 cols per block, 4 waves (m 2 x nh 2). ----
__global__ __launch_bounds__(256) void k_attn2(const unsigned short* __restrict__ Vkm,
                                               const unsigned int* __restrict__ Bits,
                                               const float* __restrict__ Wh1,
                                               const float* __restrict__ gmax2,
                                               float* __restrict__ U) {
  const int i = blockIdx.y;
  const int r0 = blockIdx.x * 64;
  const int cb = blockIdx.z * 1024;
  const int t = threadIdx.x;
  const int lane = t & 63, wid = t >> 6;
  const int m = wid & 1, nh = wid >> 1, nbase = nh * 64;
  const int l31 = lane & 31, kh = lane >> 5;

  __shared__ char Vl[32768];   // [s:2][n:128][8 slots of 16B], slot xor-swizzled by (n&7)
  __shared__ float wh1s[64];

  if (t < 64) wh1s[t] = Wh1[(size_t)i * NN + r0 + t];

  const int r = r0 + m * 32 + l31;
  const unsigned int* brow = Bits + ((size_t)i * NN + r) * 256 + (cb >> 4);

  f32x16 accP0 = {}, accP1 = {}, accM0 = {}, accM1 = {};

  for (int chunk = 0; chunk < 16; ++chunk) {
    // T14: issue global loads early (regs), write to LDS after barrier
    uint4 stg[8];
    #pragma unroll
    for (int j = 0; j < 8; ++j) {
      int idx = t + j * 256;
      int s = idx >> 10, n = (idx >> 3) & 127, g = idx & 7;
      stg[j] = *(const uint4*)(Vkm + ((size_t)(i * 2 + s) * OUT_F + n) * NN + cb + chunk * 64 + g * 8);
    }
    const uint4 wv4 = *(const uint4*)(brow + chunk * 4);
    unsigned int wv[4] = {wv4.x, wv4.y, wv4.z, wv4.w};

    __syncthreads();  // previous chunk's compute done
    #pragma unroll
    for (int j = 0; j < 8; ++j) {
      int idx = t + j * 256;
      int s = idx >> 10, n = (idx >> 3) & 127, g = idx & 7;
      *(uint4*)(Vl + ((s << 14) + (n << 7) + (((g ^ (n & 7)) & 7) << 4))) = stg[j];
    }
    __syncthreads();  // stage visible

    #pragma unroll
    for (int kst = 0; kst < 4; ++kst) {
      unsigned int bP = (wv[kst] >> (kh * 8)) & 0xFFu;
      unsigned int bM = (wv[kst] >> (16 + kh * 8)) & 0xFFu;
      bf16x8 aP = bits2bf8(bP);
      bf16x8 aM = bits2bf8(bM);
      const int slot = kst * 2 + kh;
      const int n0 = nbase + l31;
      const int n1 = nbase + 32 + l31;
      bf16x8 bP0 = *(const bf16x8*)(Vl + ((0 << 14) + (n0 << 7) + (((slot ^ (n0 & 7)) & 7) << 4)));
      bf16x8 bP1 = *(const bf16x8*)(Vl + ((0 << 14) + (n1 << 7) + (((slot ^ (n1 & 7)) & 7) << 4)));
      bf16x8 bM0 = *(const bf16x8*)(Vl + ((1 << 14) + (n0 << 7) + (((slot ^ (n0 & 7)) & 7) << 4)));
      bf16x8 bM1 = *(const bf16x8*)(Vl + ((1 << 14) + (n1 << 7) + (((slot ^ (n1 & 7)) & 7) << 4)));
      accP0 = __builtin_amdgcn_mfma_f32_32x32x16_bf16(aP, bP0, accP0, 0, 0, 0);
      accP1 = __builtin_amdgcn_mfma_f32_32x32x16_bf16(aP, bP1, accP1, 0, 0, 0);
      accM0 = __builtin_amdgcn_mfma_f32_32x32x16_bf16(aM, bM0, accM0, 0, 0, 0);
      accM1 = __builtin_amdgcn_mfma_f32_32x32x16_bf16(aM, bM1, accM1, 0, 0, 0);
    }
  }

  const float gi = gmax2[i];
  #pragma unroll
  for (int q = 0; q < 16; ++q) {
    const int crow = (q & 3) + 8 * (q >> 2) + 4 * kh;
    const int rloc2 = m * 32 + crow;
    const float w1 = wh1s[rloc2];
    const float e0 = w1 + gi;
    const float mx = (e0 > 0.f) ? e0 : ALPHA * e0;
    const float fp = __expf(w1 - mx);
    const float fm = __expf(ALPHA * w1 - mx);
    float* urow = U + ((size_t)i * NN + r0 + rloc2) * OUT_F + nbase + l31;
    atomicAdd(urow, fp * accP0[q] + fm * accM0[q]);
    atomicAdd(urow + 32, fp * accP1[q] + fm * accM1[q]);
  }
}

// ---- final: out = elu( sum_i coef_i * U_i/S_i + 0.125*Whnew2 ) ----
__global__ __launch_bounds__(256) void k_final(const float* __restrict__ U,
                                               const float* __restrict__ Sp,
                                               const float* __restrict__ Sm,
                                               const float* __restrict__ Wh1,
                                               const float* __restrict__ gmax2,
                                               const float* __restrict__ Whnewf,
                                               float* __restrict__ out) {
  int idx = blockIdx.x * 256 + threadIdx.x;
  int r = idx >> 7;
  float v = 0.125f * Whnewf[(size_t)2 * NN * OUT_F + idx];
  #pragma unroll
  for (int i = 0; i < 3; ++i) {
    const float coef = (i == 0) ? 0.5f : (i == 1) ? 0.25f : 0.125f;
    const float w1 = Wh1[(size_t)i * NN + r];
    const float gi = gmax2[i];
    const float e0 = w1 + gi;
    const float mx = (e0 > 0.f) ? e0 : ALPHA * e0;
    const float fp = __expf(w1 - mx);
    const float fm = __expf(ALPHA * w1 - mx);
    const float S = fp * Sp[(size_t)i * NN + r] + fm * Sm[(size_t)i * NN + r];
    v += coef * U[(size_t)i * NN * OUT_F + idx] / S;
  }
  out[idx] = (v > 0.f) ? v : (__expf(v) - 1.0f);
}

extern "C" void kernel_launch(void* const* d_in, const int* in_sizes, int n_in,
                              void* d_out, int out_size, void* d_ws, size_t ws_size,
                              hipStream_t stream) {
  const float* h    = (const float*)d_in[0];
  const int*   mask = (const int*)d_in[1];
  const float* W    = (const float*)d_in[2];
  const float* a    = (const float*)d_in[3];
  float* out = (float*)d_out;

  float* Whnewf = (float*)d_ws;                        // 3*NN*128
  float* Wh1    = Whnewf + (size_t)3 * NN * OUT_F;     // 3*NN
  float* Wh2    = Wh1 + 3 * NN;                        // 3*NN
  float* gmax2  = Wh2 + 3 * NN;                        // 4
  float* U      = gmax2 + 4;                           // 3*NN*128
  float* Sp     = U + (size_t)3 * NN * OUT_F;          // 3*NN
  float* Sm     = Sp + 3 * NN;                         // 3*NN
  unsigned short* hb    = (unsigned short*)(Sm + 3 * NN);     // NN*256
  unsigned short* Wtb   = hb + (size_t)NN * IN_F;             // 3*128*256
  unsigned short* Vkm   = Wtb + (size_t)3 * OUT_F * IN_F;     // 3*2*128*NN
  unsigned short* ew2pb = Vkm + (size_t)3 * 2 * OUT_F * NN;   // 3*NN
  unsigned short* ew2mb = ew2pb + 3 * NN;                     // 3*NN
  unsigned int*   Bits  = (unsigned int*)(ew2mb + 3 * NN);    // 3*NN*256

  k_cvt_h<<<512, 256, 0, stream>>>(h, hb);
  k_cvt_w<<<dim3(8, 3), 256, 0, stream>>>(W, Wtb);
  k_zero<<<(3 * NN * OUT_F) / 1024, 256, 0, stream>>>(U);
  k_front<<<dim3(128, 3), 256, 0, stream>>>(hb, Wtb, a, Whnewf, Wh1, Wh2);
  k_gmax<<<3, 256, 0, stream>>>(Wh2, gmax2);
  k_ew2<<<48, 256, 0, stream>>>(Wh2, ew2pb, ew2mb);
  k_scale<<<dim3(128, 3), 256, 0, stream>>>(Whnewf, ew2pb, ew2mb, Vkm);
  k_bits<<<dim3(512, 3), 256, 0, stream>>>(mask, Wh1, Wh2, ew2pb, ew2mb, Bits, Sp, Sm);
  k_attn2<<<dim3(64, 3, 4), 256, 0, stream>>>(Vkm, Bits, Wh1, gmax2, U);
  k_final<<<(NN * OUT_F) / 256, 256, 0, stream>>>(U, Sp, Sm, Wh1, gmax2, Whnewf, out);
}